// Round 22
// baseline (159.221 us; speedup 1.0000x reference)
//
#include <hip/hip_runtime.h>

typedef __attribute__((ext_vector_type(4))) float  f32x4;
typedef __attribute__((ext_vector_type(4))) short  s16x4;
typedef __attribute__((ext_vector_type(8))) short  s16x8;
typedef __bf16 bf16x8 __attribute__((ext_vector_type(8)));

#define NBATCH 16
#define SEQ    4096
#define KIN    256
#define HY     64
#define HOUT   512
#define NROWS  (NBATCH*SEQ)   /* 65536 */
#define LC     64
#define NC     (SEQ/LC)       /* 64 */

#define GP(x) ((const __attribute__((address_space(1))) void*)(x))
#define LP(x) ((__attribute__((address_space(3))) void*)(x))

static __device__ __forceinline__ short f2bf(float f) {
  unsigned u = __float_as_uint(f);
  u = u + 0x7FFF + ((u >> 16) & 1);          // RNE
  return (short)(u >> 16);
}
static __device__ __forceinline__ float bf2f(short h) {
  return __uint_as_float(((unsigned)(unsigned short)h) << 16);
}
static __device__ __forceinline__ f32x4 mfma16(bf16x8 a, bf16x8 b, f32x4 c) {
  return __builtin_amdgcn_mfma_f32_16x16x32_bf16(a, b, c, 0, 0, 0);
}
static __device__ __forceinline__ bf16x8 ldfrag(const short* p) {
  return *reinterpret_cast<const bf16x8*>(p);
}
static __device__ __forceinline__ float fsigmoid(float z) {
  return 1.f / (1.f + __expf(-z));
}

// ---------------- weight prep (all plain bf16)
__global__ void prep_w(const float* __restrict__ lin0W, const float* __restrict__ sig0W,
                       const float* __restrict__ fchW,  const float* __restrict__ fc2W,
                       short* __restrict__ W1h, short* __restrict__ W2h,
                       short* __restrict__ Fh,  short* __restrict__ F2h) {
  int i = blockIdx.x * 256 + threadIdx.x;
  if (i < 16384) {
    W1h[i] = f2bf(lin0W[i]);
    W2h[i] = f2bf(sig0W[i]);
  } else if (i < 16384 + 32768) {
    Fh[i - 16384] = f2bf(fchW[i - 16384]);
  } else if (i < 16384 + 32768 + 131072) {
    F2h[i - 49152] = f2bf(fc2W[i - 49152]);
  }
}

// ---------------- gx: 64-row blocks. g = relu((x@lin0^T+b)*sigmoid(x@sig0^T+b)) -> Gh (bf16,
// LDS-bounced coalesced), and xh = bf16(x) emitted during staging (16B stores). (r13-verified)
__global__ __launch_bounds__(256) void gx(
    const float* __restrict__ x,
    const short* __restrict__ W1h, const short* __restrict__ W2h,
    const float* __restrict__ lin0b, const float* __restrict__ sig0b,
    short* __restrict__ Gh, short* __restrict__ xh) {
  __shared__ __align__(16) short smem[64 * 256 + 64 * 64];  // Ah 32KB + gL 8KB
  short* Ah = smem;
  short* gL = smem + 64 * 256;
  int tid = threadIdx.x;
  int row0 = blockIdx.x * 64;
  #pragma unroll
  for (int i = 0; i < 8; ++i) {
    int slot = i * 256 + tid;              // 2048 slots of 8 floats over 64x256
    int r = slot >> 5, k8 = slot & 31;
    const float* xp = x + (size_t)(row0 + r) * KIN + k8 * 8;
    f32x4 v0 = *reinterpret_cast<const f32x4*>(xp);
    f32x4 v1 = *reinterpret_cast<const f32x4*>(xp + 4);
    s16x8 hh;
    #pragma unroll
    for (int j = 0; j < 4; ++j) { hh[j] = f2bf(v0[j]); hh[4 + j] = f2bf(v1[j]); }
    *reinterpret_cast<s16x8*>(&Ah[(r * 256 + k8 * 8) ^ ((r & 7) << 3)]) = hh;
    *reinterpret_cast<s16x8*>(xh + (size_t)(row0 + r) * KIN + k8 * 8) = hh;
  }
  __syncthreads();
  int w = tid >> 6, l = tid & 63, lr = l & 15, lg = l >> 4;
  {
    int c = w * 16 + lr;
    f32x4 a1[4], a2[4];
    #pragma unroll
    for (int rt = 0; rt < 4; ++rt) { a1[rt] = (f32x4)0.f; a2[rt] = (f32x4)0.f; }
    #pragma unroll
    for (int ks = 0; ks < 8; ++ks) {
      int kk = ks * 32 + lg * 8;
      bf16x8 b1 = ldfrag(W1h + c * 256 + kk);
      bf16x8 b2 = ldfrag(W2h + c * 256 + kk);
      #pragma unroll
      for (int rt = 0; rt < 4; ++rt) {
        int r = rt * 16 + lr;
        bf16x8 a = ldfrag(&Ah[(r * 256 + kk) ^ ((r & 7) << 3)]);
        a1[rt] = mfma16(b1, a, a1[rt]);
        a2[rt] = mfma16(b2, a, a2[rt]);
      }
    }
    f32x4 blv = *reinterpret_cast<const f32x4*>(lin0b + w * 16 + lg * 4);
    f32x4 bsv = *reinterpret_cast<const f32x4*>(sig0b + w * 16 + lg * 4);
    #pragma unroll
    for (int rt = 0; rt < 4; ++rt) {
      int xrl = rt * 16 + lr;                // local x row
      s16x4 gg;
      #pragma unroll
      for (int j = 0; j < 4; ++j) {
        float g = (a1[rt][j] + blv[j]) * fsigmoid(a2[rt][j] + bsv[j]);
        gg[j] = f2bf(g > 0.f ? g : 0.f);
      }
      *reinterpret_cast<s16x4*>(&gL[(xrl * 64 + w * 16 + lg * 4) ^ ((xrl & 7) << 3)]) = gg;
    }
  }
  __syncthreads();
  #pragma unroll
  for (int i = 0; i < 2; ++i) {
    int slot = i * 256 + tid;
    int row = slot >> 3, c8 = slot & 7;
    s16x8 v = *reinterpret_cast<const s16x8*>(&gL[(row * 64 + c8 * 8) ^ ((row & 7) << 3)]);
    *reinterpret_cast<s16x8*>(Gh + (size_t)(row0 + row) * HY + c8 * 8) = v;
  }
}

// ---------------- bg: 128x128 staged GEMM, 1024 threads / 16 waves (wave = 16x64 tile),
// double-buffered 2x32KB LDS, 2-phase schedule, XCD-pinned colTile mapping.
// Only acc2 (16 VGPRs) is live across the K-loop; accF is declared after it -> launch_bounds
// (1024,8) targets <=64 VGPR = 8 waves/SIMD = 32 waves/CU (2x r21's residency).
__global__ __launch_bounds__(1024, 8) void bg(
    const short* __restrict__ xh, const short* __restrict__ Gh,
    const short* __restrict__ F2h, const short* __restrict__ Fh,
    const float* __restrict__ fchb, const float* __restrict__ fc2b,
    short* __restrict__ Bb) {
  __shared__ __align__(16) short smem[2][16384];   // 2 x 32KB (As 8192 + Bs 8192 shorts each)
  short* bT = &smem[1][0];                          // 128x128 shorts = 32KB (bounce phase, buf1)
  int tid = threadIdx.x;
  int w = tid >> 6, l = tid & 63;                   // w in [0,16)
  int lr = l & 15, lg = l >> 4;
  int r0 = (w >> 1) * 16;                           // 8 row-tiles of 16
  int c0 = (w & 1) * 64;                            // 2 col-halves of 64
  int bid = blockIdx.x;
  int xcd = bid & 7, idx = bid >> 3;
  int colTile = xcd >> 1;                           // one col-panel per XCD pair
  int rowTile = ((xcd & 1) << 8) + idx;             // bijective over [0,512)
  int row0 = rowTile * 128;
  int col0 = colTile * 128;

  auto stage = [&](int t, int b) {
    short* As = &smem[b][0];
    short* Bs = &smem[b][8192];
    int blk = w;                                    // 16 slot-blocks of 64 slots
    int flat = blk * 64 + l;                        // 16B slot in [0,1024)
    int row = flat >> 3, sp = flat & 7;
    int seg = sp ^ (row & 7);                       // inverse of read-side XOR
    const short* asrc = (t < 4) ? xh + (size_t)(row0 + row) * KIN + t * 64 + seg * 8
                                : Gh + (size_t)(row0 + row) * HY + seg * 8;
    const short* bsrc = (t < 4) ? F2h + (size_t)(col0 + row) * KIN + t * 64 + seg * 8
                                : Fh + (size_t)(col0 + row) * HY + seg * 8;
    __builtin_amdgcn_global_load_lds(GP(asrc), LP(&As[blk * 512]), 16, 0, 0);
    __builtin_amdgcn_global_load_lds(GP(bsrc), LP(&Bs[blk * 512]), 16, 0, 0);
  };
  auto compute = [&](int b, f32x4 (&acc)[4]) {
    short* As = &smem[b][0];
    short* Bs = &smem[b][8192];
    #pragma unroll
    for (int ksl = 0; ksl < 2; ++ksl) {
      bf16x8 Af, Bf[4];
      {
        int row = r0 + lr;
        Af = ldfrag(&As[row * 64 + ((ksl * 32 + lg * 8) ^ ((row & 7) << 3))]);
      }
      #pragma unroll
      for (int i = 0; i < 4; ++i) {
        int col = c0 + i * 16 + lr;
        Bf[i] = ldfrag(&Bs[col * 64 + ((ksl * 32 + lg * 8) ^ ((col & 7) << 3))]);
      }
      #pragma unroll
      for (int ct = 0; ct < 4; ++ct)
        acc[ct] = mfma16(Af, Bf[ct], acc[ct]);
    }
  };

  f32x4 acc2[4];
  #pragma unroll
  for (int ct = 0; ct < 4; ++ct) acc2[ct] = (f32x4)0.f;

  stage(0, 0);
  __syncthreads();                        // buf0 ready
  #pragma unroll
  for (int t = 0; t < 4; ++t) {
    stage(t + 1, (t + 1) & 1);            // issue next-tile loads into other buffer
    compute(t & 1, acc2);
    __syncthreads();                      // drains prefetch vmcnt; next buf ready
  }
  f32x4 accF[4];                          // declared AFTER the K-loop: not live in-loop
  #pragma unroll
  for (int ct = 0; ct < 4; ++ct) accF[ct] = (f32x4)0.f;
  compute(0, accF);                       // buf0; no trailing barrier (bT = buf1, free)

  // epilogue: gate -> bf16 -> swizzled bT (buf1)
  #pragma unroll
  for (int ct = 0; ct < 4; ++ct) {
    int lc = c0 + ct * 16 + lr;
    int col = col0 + lc;
    float bc = fchb[col], b2c = fc2b[col];
    int tl0 = r0 + lg * 4;
    #pragma unroll
    for (int j = 0; j < 4; ++j) {
      int tl = tl0 + j;
      float alpha = fsigmoid(acc2[ct][j] + b2c);
      bT[(tl * 128 + lc) ^ ((tl & 7) << 3)] = f2bf((accF[ct][j] + bc) * alpha);
    }
  }
  __syncthreads();
  // coalesced store: 2048 slots of 16B over 128x128 shorts
  #pragma unroll
  for (int i = 0; i < 2; ++i) {
    int slot = i * 1024 + tid;
    int row = slot >> 4, c8 = slot & 15;
    s16x8 vv = *reinterpret_cast<const s16x8*>(&bT[(row * 128 + c8 * 8) ^ ((row & 7) << 3)]);
    *reinterpret_cast<s16x8*>(Bb + (size_t)(row0 + row) * HOUT + col0 + c8 * 8) = vv;
  }
}

// ---------------- passA: per-chunk (LC=64 rows) max-plus operator (C,S). 1 wave/chunk, prefetched.
__global__ __launch_bounds__(64) void scan_passA(const short* __restrict__ Bb,
                                                 float* __restrict__ Cc, float* __restrict__ Sc) {
  int bc = blockIdx.x;
  int l = threadIdx.x;
  int row0 = bc * LC;
  const short* bp = Bb + (size_t)row0 * HOUT + l * 8;
  s16x8 v0 = *reinterpret_cast<const s16x8*>(bp);
  float C[8], S[8];
  #pragma unroll
  for (int i = 0; i < 8; ++i) { S[i] = bf2f(v0[i]); C[i] = 0.f; }
  s16x8 vc = *reinterpret_cast<const s16x8*>(bp + (size_t)HOUT);   // row 1
  for (int t = 1; t < LC; ++t) {
    s16x8 vn;
    if (t + 1 < LC) vn = *reinterpret_cast<const s16x8*>(bp + (size_t)(t + 1) * HOUT);
    float bb[8];
    #pragma unroll
    for (int i = 0; i < 8; ++i) bb[i] = bf2f(vc[i]);
    float pC = __shfl(C[7], (l + 63) & 63);
    float pS = __shfl(S[7], (l + 63) & 63);
    #pragma unroll
    for (int i = 7; i >= 1; --i) { C[i] = fmaxf(0.f, bb[i] + C[i - 1]); S[i] = bb[i] + S[i - 1]; }
    C[0] = fmaxf(0.f, bb[0] + pC);
    S[0] = bb[0] + pS;
    vc = vn;
  }
  float* cp = Cc + (size_t)bc * HOUT + l * 8;
  float* sp = Sc + (size_t)bc * HOUT + l * 8;
  #pragma unroll
  for (int i = 0; i < 8; ++i) { cp[i] = C[i]; sp[i] = S[i]; }
}

// ---------------- combine: sequential over NC=64 chunks per batch, prefetch depth 4.
__global__ __launch_bounds__(64) void scan_combine(const float* __restrict__ hidden,
                                                   const float* __restrict__ Cc, const float* __restrict__ Sc,
                                                   float* __restrict__ hIn, float* __restrict__ lastOut) {
  int batch = blockIdx.x;
  int l = threadIdx.x;
  float h[8];
  const float* hp = hidden + batch * HOUT + l * 8;
  #pragma unroll
  for (int i = 0; i < 8; ++i) h[i] = hp[i];
  size_t base0 = ((size_t)batch * NC) * HOUT + l * 8;
  f32x4 pc0[4], pc1[4], ps0[4], ps1[4];
  #pragma unroll
  for (int s = 0; s < 4; ++s) {
    size_t b = base0 + (size_t)s * HOUT;
    pc0[s] = *reinterpret_cast<const f32x4*>(Cc + b);
    pc1[s] = *reinterpret_cast<const f32x4*>(Cc + b + 4);
    ps0[s] = *reinterpret_cast<const f32x4*>(Sc + b);
    ps1[s] = *reinterpret_cast<const f32x4*>(Sc + b + 4);
  }
  for (int cg = 0; cg < NC; cg += 4) {
    #pragma unroll
    for (int s = 0; s < 4; ++s) {
      int c = cg + s;
      size_t base = base0 + (size_t)c * HOUT;
      f32x4 h0, h1;
      #pragma unroll
      for (int i = 0; i < 4; ++i) { h0[i] = h[i]; h1[i] = h[4 + i]; }
      *reinterpret_cast<f32x4*>(hIn + base) = h0;
      *reinterpret_cast<f32x4*>(hIn + base + 4) = h1;
      float hs[8];
      #pragma unroll
      for (int i = 0; i < 8; ++i) hs[i] = __shfl(h[i], (l + 64 - (LC / 8)) & 63);   // d - LC
      #pragma unroll
      for (int i = 0; i < 4; ++i) {
        h[i]     = fmaxf(pc0[s][i], ps0[s][i] + hs[i]);
        h[4 + i] = fmaxf(pc1[s][i], ps1[s][i] + hs[4 + i]);
      }
      if (c + 4 < NC) {
        size_t nb = base + (size_t)4 * HOUT;
        pc0[s] = *reinterpret_cast<const f32x4*>(Cc + nb);
        pc1[s] = *reinterpret_cast<const f32x4*>(Cc + nb + 4);
        ps0[s] = *reinterpret_cast<const f32x4*>(Sc + nb);
        ps1[s] = *reinterpret_cast<const f32x4*>(Sc + nb + 4);
      }
    }
  }
  float* lp = lastOut + batch * HOUT + l * 8;
  #pragma unroll
  for (int i = 0; i < 8; ++i) lp[i] = h[i];
}

// ---------------- pass B: replay recurrence from bf16 b (Bb), prefetched; fp32 h -> d_out.
__global__ __launch_bounds__(64) void scan_passB(const short* __restrict__ bws,
                                                 const float* __restrict__ hIn,
                                                 float* __restrict__ hout) {
  int bc = blockIdx.x;
  int l = threadIdx.x;
  int row0 = bc * LC;
  const float* hp = hIn + (size_t)bc * HOUT + l * 8;
  float h[8];
  #pragma unroll
  for (int i = 0; i < 8; ++i) h[i] = hp[i];
  s16x8 vc = *reinterpret_cast<const s16x8*>(bws + (size_t)row0 * HOUT + l * 8);
  for (int t = 0; t < LC; ++t) {
    s16x8 vn;
    if (t + 1 < LC)
      vn = *reinterpret_cast<const s16x8*>(bws + (size_t)(row0 + t + 1) * HOUT + l * 8);
    float bb[8];
    #pragma unroll
    for (int i = 0; i < 8; ++i) bb[i] = bf2f(vc[i]);
    float ph = __shfl(h[7], (l + 63) & 63);
    #pragma unroll
    for (int i = 7; i >= 1; --i) h[i] = fmaxf(0.f, bb[i] + h[i - 1]);
    h[0] = fmaxf(0.f, bb[0] + ph);
    f32x4 o0, o1;
    #pragma unroll
    for (int i = 0; i < 4; ++i) { o0[i] = h[i]; o1[i] = h[4 + i]; }
    float* bt = hout + (size_t)(row0 + t) * HOUT + l * 8;
    *reinterpret_cast<f32x4*>(bt) = o0;
    *reinterpret_cast<f32x4*>(bt + 4) = o1;
    vc = vn;
  }
}

extern "C" void kernel_launch(void* const* d_in, const int* in_sizes, int n_in,
                              void* d_out, int out_size, void* d_ws, size_t ws_size,
                              hipStream_t stream) {
  (void)in_sizes; (void)n_in; (void)out_size; (void)ws_size;
  const float* x      = (const float*)d_in[0];
  const float* hidden = (const float*)d_in[1];
  const float* lin0W  = (const float*)d_in[2];
  const float* lin0b  = (const float*)d_in[3];
  const float* sig0W  = (const float*)d_in[4];
  const float* sig0b  = (const float*)d_in[5];
  const float* fchW   = (const float*)d_in[6];
  const float* fchb   = (const float*)d_in[7];
  const float* fc2W   = (const float*)d_in[8];
  const float* fc2b   = (const float*)d_in[9];
  float* outO  = (float*)d_out;
  float* lastO = outO + (size_t)NROWS * HOUT;

  char* wsb = (char*)d_ws;
  size_t off = 0;
  auto alloc = [&](size_t bytes) { char* p = wsb + off; off += (bytes + 255) & ~(size_t)255; return p; };
  float* Cc  = (float*)alloc((size_t)NBATCH * NC * HOUT * 4);
  float* Sc  = (float*)alloc((size_t)NBATCH * NC * HOUT * 4);
  float* hIn = (float*)alloc((size_t)NBATCH * NC * HOUT * 4);
  short* W1h = (short*)alloc(HY * KIN * 2);
  short* W2h = (short*)alloc(HY * KIN * 2);
  short* Fh  = (short*)alloc(HOUT * HY * 2);
  short* F2h = (short*)alloc(HOUT * KIN * 2);
  short* Gh  = (short*)alloc((size_t)NROWS * HY * 2);
  short* xh  = (short*)alloc((size_t)NROWS * KIN * 2);
  short* Bb  = (short*)alloc((size_t)NROWS * HOUT * 2);

  prep_w<<<704, 256, 0, stream>>>(lin0W, sig0W, fchW, fc2W, W1h, W2h, Fh, F2h);
  gx<<<NROWS / 64, 256, 0, stream>>>(x, W1h, W2h, lin0b, sig0b, Gh, xh);
  bg<<<2048, 1024, 0, stream>>>(xh, Gh, F2h, Fh, fchb, fc2b, Bb);
  scan_passA<<<NBATCH * NC, 64, 0, stream>>>(Bb, Cc, Sc);
  scan_combine<<<NBATCH, 64, 0, stream>>>(hidden, Cc, Sc, hIn, lastO);
  scan_passB<<<NBATCH * NC, 64, 0, stream>>>(Bb, hIn, outO);
}

// Round 23
// 154.984 us; speedup vs baseline: 1.0273x; 1.0273x over previous
//
#include <hip/hip_runtime.h>

typedef __attribute__((ext_vector_type(4))) float  f32x4;
typedef __attribute__((ext_vector_type(4))) short  s16x4;
typedef __attribute__((ext_vector_type(8))) short  s16x8;
typedef __bf16 bf16x8 __attribute__((ext_vector_type(8)));

#define NBATCH 16
#define SEQ    4096
#define KIN    256
#define HY     64
#define HOUT   512
#define NROWS  (NBATCH*SEQ)   /* 65536 */
#define LC     64
#define NC     (SEQ/LC)       /* 64 */

#define GP(x) ((const __attribute__((address_space(1))) void*)(x))
#define LP(x) ((__attribute__((address_space(3))) void*)(x))

static __device__ __forceinline__ short f2bf(float f) {
  unsigned u = __float_as_uint(f);
  u = u + 0x7FFF + ((u >> 16) & 1);          // RNE
  return (short)(u >> 16);
}
static __device__ __forceinline__ float bf2f(short h) {
  return __uint_as_float(((unsigned)(unsigned short)h) << 16);
}
static __device__ __forceinline__ f32x4 mfma16(bf16x8 a, bf16x8 b, f32x4 c) {
  return __builtin_amdgcn_mfma_f32_16x16x32_bf16(a, b, c, 0, 0, 0);
}
static __device__ __forceinline__ bf16x8 ldfrag(const short* p) {
  return *reinterpret_cast<const bf16x8*>(p);
}
static __device__ __forceinline__ float fsigmoid(float z) {
  return 1.f / (1.f + __expf(-z));
}

// ---------------- weight prep (all plain bf16)
__global__ void prep_w(const float* __restrict__ lin0W, const float* __restrict__ sig0W,
                       const float* __restrict__ fchW,  const float* __restrict__ fc2W,
                       short* __restrict__ W1h, short* __restrict__ W2h,
                       short* __restrict__ Fh,  short* __restrict__ F2h) {
  int i = blockIdx.x * 256 + threadIdx.x;
  if (i < 16384) {
    W1h[i] = f2bf(lin0W[i]);
    W2h[i] = f2bf(sig0W[i]);
  } else if (i < 16384 + 32768) {
    Fh[i - 16384] = f2bf(fchW[i - 16384]);
  } else if (i < 16384 + 32768 + 131072) {
    F2h[i - 49152] = f2bf(fc2W[i - 49152]);
  }
}

// ---------------- gx: 64-row blocks. g = relu((x@lin0^T+b)*sigmoid(x@sig0^T+b)) -> Gh (bf16,
// LDS-bounced coalesced), and xh = bf16(x) emitted during staging (16B stores). (r13-verified)
__global__ __launch_bounds__(256) void gx(
    const float* __restrict__ x,
    const short* __restrict__ W1h, const short* __restrict__ W2h,
    const float* __restrict__ lin0b, const float* __restrict__ sig0b,
    short* __restrict__ Gh, short* __restrict__ xh) {
  __shared__ __align__(16) short smem[64 * 256 + 64 * 64];  // Ah 32KB + gL 8KB
  short* Ah = smem;
  short* gL = smem + 64 * 256;
  int tid = threadIdx.x;
  int row0 = blockIdx.x * 64;
  #pragma unroll
  for (int i = 0; i < 8; ++i) {
    int slot = i * 256 + tid;              // 2048 slots of 8 floats over 64x256
    int r = slot >> 5, k8 = slot & 31;
    const float* xp = x + (size_t)(row0 + r) * KIN + k8 * 8;
    f32x4 v0 = *reinterpret_cast<const f32x4*>(xp);
    f32x4 v1 = *reinterpret_cast<const f32x4*>(xp + 4);
    s16x8 hh;
    #pragma unroll
    for (int j = 0; j < 4; ++j) { hh[j] = f2bf(v0[j]); hh[4 + j] = f2bf(v1[j]); }
    *reinterpret_cast<s16x8*>(&Ah[(r * 256 + k8 * 8) ^ ((r & 7) << 3)]) = hh;
    *reinterpret_cast<s16x8*>(xh + (size_t)(row0 + r) * KIN + k8 * 8) = hh;
  }
  __syncthreads();
  int w = tid >> 6, l = tid & 63, lr = l & 15, lg = l >> 4;
  {
    int c = w * 16 + lr;
    f32x4 a1[4], a2[4];
    #pragma unroll
    for (int rt = 0; rt < 4; ++rt) { a1[rt] = (f32x4)0.f; a2[rt] = (f32x4)0.f; }
    #pragma unroll
    for (int ks = 0; ks < 8; ++ks) {
      int kk = ks * 32 + lg * 8;
      bf16x8 b1 = ldfrag(W1h + c * 256 + kk);
      bf16x8 b2 = ldfrag(W2h + c * 256 + kk);
      #pragma unroll
      for (int rt = 0; rt < 4; ++rt) {
        int r = rt * 16 + lr;
        bf16x8 a = ldfrag(&Ah[(r * 256 + kk) ^ ((r & 7) << 3)]);
        a1[rt] = mfma16(b1, a, a1[rt]);
        a2[rt] = mfma16(b2, a, a2[rt]);
      }
    }
    f32x4 blv = *reinterpret_cast<const f32x4*>(lin0b + w * 16 + lg * 4);
    f32x4 bsv = *reinterpret_cast<const f32x4*>(sig0b + w * 16 + lg * 4);
    #pragma unroll
    for (int rt = 0; rt < 4; ++rt) {
      int xrl = rt * 16 + lr;                // local x row
      s16x4 gg;
      #pragma unroll
      for (int j = 0; j < 4; ++j) {
        float g = (a1[rt][j] + blv[j]) * fsigmoid(a2[rt][j] + bsv[j]);
        gg[j] = f2bf(g > 0.f ? g : 0.f);
      }
      *reinterpret_cast<s16x4*>(&gL[(xrl * 64 + w * 16 + lg * 4) ^ ((xrl & 7) << 3)]) = gg;
    }
  }
  __syncthreads();
  #pragma unroll
  for (int i = 0; i < 2; ++i) {
    int slot = i * 256 + tid;
    int row = slot >> 3, c8 = slot & 7;
    s16x8 v = *reinterpret_cast<const s16x8*>(&gL[(row * 64 + c8 * 8) ^ ((row & 7) << 3)]);
    *reinterpret_cast<s16x8*>(Gh + (size_t)(row0 + row) * HY + c8 * 8) = v;
  }
}

// ---------------- bg: 128x128 staged GEMM, 512 threads / 8 waves (wave = 32x64 quadrant),
// double-buffered 2x32KB LDS, 2-phase schedule, XCD-pinned colTile mapping. (r15/r17-verified)
__global__ __launch_bounds__(512, 4) void bg(
    const short* __restrict__ xh, const short* __restrict__ Gh,
    const short* __restrict__ F2h, const short* __restrict__ Fh,
    const float* __restrict__ fchb, const float* __restrict__ fc2b,
    short* __restrict__ Bb) {
  __shared__ __align__(16) short smem[2][16384];   // 2 x 32KB (As 8192 + Bs 8192 shorts each)
  short* bT = &smem[1][0];                          // 128x128 shorts = 32KB (bounce phase, buf1)
  int tid = threadIdx.x;
  int w = tid >> 6, l = tid & 63;
  int lr = l & 15, lg = l >> 4;
  int r0 = (w >> 1) * 32;                           // 4 row-quarters of 32
  int c0 = (w & 1) * 64;                            // 2 col-halves of 64
  int bid = blockIdx.x;
  int xcd = bid & 7, idx = bid >> 3;
  int colTile = xcd >> 1;                           // one col-panel per XCD pair
  int rowTile = ((xcd & 1) << 8) + idx;             // bijective over [0,512)
  int row0 = rowTile * 128;
  int col0 = colTile * 128;

  auto stage = [&](int t, int b) {
    short* As = &smem[b][0];
    short* Bs = &smem[b][8192];
    #pragma unroll
    for (int j = 0; j < 2; ++j) {
      int blk = w * 2 + j;                          // 16 slot-blocks of 64 slots
      int flat = blk * 64 + l;                      // 16B slot in [0,1024)
      int row = flat >> 3, sp = flat & 7;
      int seg = sp ^ (row & 7);                     // inverse of read-side XOR
      const short* asrc = (t < 4) ? xh + (size_t)(row0 + row) * KIN + t * 64 + seg * 8
                                  : Gh + (size_t)(row0 + row) * HY + seg * 8;
      const short* bsrc = (t < 4) ? F2h + (size_t)(col0 + row) * KIN + t * 64 + seg * 8
                                  : Fh + (size_t)(col0 + row) * HY + seg * 8;
      __builtin_amdgcn_global_load_lds(GP(asrc), LP(&As[blk * 512]), 16, 0, 0);
      __builtin_amdgcn_global_load_lds(GP(bsrc), LP(&Bs[blk * 512]), 16, 0, 0);
    }
  };
  auto compute = [&](int b, f32x4 (&acc)[2][4]) {
    short* As = &smem[b][0];
    short* Bs = &smem[b][8192];
    #pragma unroll
    for (int ksl = 0; ksl < 2; ++ksl) {
      bf16x8 Af[2], Bf[4];
      #pragma unroll
      for (int i = 0; i < 2; ++i) {
        int row = r0 + i * 16 + lr;
        Af[i] = ldfrag(&As[row * 64 + ((ksl * 32 + lg * 8) ^ ((row & 7) << 3))]);
      }
      #pragma unroll
      for (int i = 0; i < 4; ++i) {
        int col = c0 + i * 16 + lr;
        Bf[i] = ldfrag(&Bs[col * 64 + ((ksl * 32 + lg * 8) ^ ((col & 7) << 3))]);
      }
      #pragma unroll
      for (int rt = 0; rt < 2; ++rt)
        #pragma unroll
        for (int ct = 0; ct < 4; ++ct)
          acc[rt][ct] = mfma16(Af[rt], Bf[ct], acc[rt][ct]);
    }
  };

  f32x4 acc2[2][4], accF[2][4];
  #pragma unroll
  for (int rt = 0; rt < 2; ++rt)
    #pragma unroll
    for (int ct = 0; ct < 4; ++ct) { acc2[rt][ct] = (f32x4)0.f; accF[rt][ct] = (f32x4)0.f; }

  stage(0, 0);
  __syncthreads();                        // buf0 ready
  #pragma unroll
  for (int t = 0; t < 4; ++t) {
    stage(t + 1, (t + 1) & 1);            // issue next-tile loads into other buffer
    compute(t & 1, acc2);
    __syncthreads();                      // drains prefetch vmcnt; next buf ready
  }
  compute(0, accF);                       // buf0; no trailing barrier (bT = buf1, free)

  // epilogue: gate -> bf16 -> swizzled bT (buf1)
  #pragma unroll
  for (int ct = 0; ct < 4; ++ct) {
    int lc = c0 + ct * 16 + lr;
    int col = col0 + lc;
    float bc = fchb[col], b2c = fc2b[col];
    #pragma unroll
    for (int rt = 0; rt < 2; ++rt) {
      int tl0 = r0 + rt * 16 + lg * 4;
      #pragma unroll
      for (int j = 0; j < 4; ++j) {
        int tl = tl0 + j;
        float alpha = fsigmoid(acc2[rt][ct][j] + b2c);
        bT[(tl * 128 + lc) ^ ((tl & 7) << 3)] = f2bf((accF[rt][ct][j] + bc) * alpha);
      }
    }
  }
  __syncthreads();
  // coalesced store: 2048 slots of 16B over 128x128 shorts
  #pragma unroll
  for (int i = 0; i < 4; ++i) {
    int slot = i * 512 + tid;
    int row = slot >> 4, c8 = slot & 15;
    s16x8 vv = *reinterpret_cast<const s16x8*>(&bT[(row * 128 + c8 * 8) ^ ((row & 7) << 3)]);
    *reinterpret_cast<s16x8*>(Bb + (size_t)(row0 + row) * HOUT + col0 + c8 * 8) = vv;
  }
}

// ---------------- passA: per-chunk (LC=64 rows) max-plus operator (C,S). 1 wave/chunk, prefetched.
__global__ __launch_bounds__(64) void scan_passA(const short* __restrict__ Bb,
                                                 float* __restrict__ Cc, float* __restrict__ Sc) {
  int bc = blockIdx.x;
  int l = threadIdx.x;
  int row0 = bc * LC;
  const short* bp = Bb + (size_t)row0 * HOUT + l * 8;
  s16x8 v0 = *reinterpret_cast<const s16x8*>(bp);
  float C[8], S[8];
  #pragma unroll
  for (int i = 0; i < 8; ++i) { S[i] = bf2f(v0[i]); C[i] = 0.f; }
  s16x8 vc = *reinterpret_cast<const s16x8*>(bp + (size_t)HOUT);   // row 1
  for (int t = 1; t < LC; ++t) {
    s16x8 vn;
    if (t + 1 < LC) vn = *reinterpret_cast<const s16x8*>(bp + (size_t)(t + 1) * HOUT);
    float bb[8];
    #pragma unroll
    for (int i = 0; i < 8; ++i) bb[i] = bf2f(vc[i]);
    float pC = __shfl(C[7], (l + 63) & 63);
    float pS = __shfl(S[7], (l + 63) & 63);
    #pragma unroll
    for (int i = 7; i >= 1; --i) { C[i] = fmaxf(0.f, bb[i] + C[i - 1]); S[i] = bb[i] + S[i - 1]; }
    C[0] = fmaxf(0.f, bb[0] + pC);
    S[0] = bb[0] + pS;
    vc = vn;
  }
  float* cp = Cc + (size_t)bc * HOUT + l * 8;
  float* sp = Sc + (size_t)bc * HOUT + l * 8;
  #pragma unroll
  for (int i = 0; i < 8; ++i) { cp[i] = C[i]; sp[i] = S[i]; }
}

// ---------------- combine: sequential over NC=64 chunks per batch, prefetch depth 4.
__global__ __launch_bounds__(64) void scan_combine(const float* __restrict__ hidden,
                                                   const float* __restrict__ Cc, const float* __restrict__ Sc,
                                                   float* __restrict__ hIn, float* __restrict__ lastOut) {
  int batch = blockIdx.x;
  int l = threadIdx.x;
  float h[8];
  const float* hp = hidden + batch * HOUT + l * 8;
  #pragma unroll
  for (int i = 0; i < 8; ++i) h[i] = hp[i];
  size_t base0 = ((size_t)batch * NC) * HOUT + l * 8;
  f32x4 pc0[4], pc1[4], ps0[4], ps1[4];
  #pragma unroll
  for (int s = 0; s < 4; ++s) {
    size_t b = base0 + (size_t)s * HOUT;
    pc0[s] = *reinterpret_cast<const f32x4*>(Cc + b);
    pc1[s] = *reinterpret_cast<const f32x4*>(Cc + b + 4);
    ps0[s] = *reinterpret_cast<const f32x4*>(Sc + b);
    ps1[s] = *reinterpret_cast<const f32x4*>(Sc + b + 4);
  }
  for (int cg = 0; cg < NC; cg += 4) {
    #pragma unroll
    for (int s = 0; s < 4; ++s) {
      int c = cg + s;
      size_t base = base0 + (size_t)c * HOUT;
      f32x4 h0, h1;
      #pragma unroll
      for (int i = 0; i < 4; ++i) { h0[i] = h[i]; h1[i] = h[4 + i]; }
      *reinterpret_cast<f32x4*>(hIn + base) = h0;
      *reinterpret_cast<f32x4*>(hIn + base + 4) = h1;
      float hs[8];
      #pragma unroll
      for (int i = 0; i < 8; ++i) hs[i] = __shfl(h[i], (l + 64 - (LC / 8)) & 63);   // d - LC
      #pragma unroll
      for (int i = 0; i < 4; ++i) {
        h[i]     = fmaxf(pc0[s][i], ps0[s][i] + hs[i]);
        h[4 + i] = fmaxf(pc1[s][i], ps1[s][i] + hs[4 + i]);
      }
      if (c + 4 < NC) {
        size_t nb = base + (size_t)4 * HOUT;
        pc0[s] = *reinterpret_cast<const f32x4*>(Cc + nb);
        pc1[s] = *reinterpret_cast<const f32x4*>(Cc + nb + 4);
        ps0[s] = *reinterpret_cast<const f32x4*>(Sc + nb);
        ps1[s] = *reinterpret_cast<const f32x4*>(Sc + nb + 4);
      }
    }
  }
  float* lp = lastOut + batch * HOUT + l * 8;
  #pragma unroll
  for (int i = 0; i < 8; ++i) lp[i] = h[i];
}

// ---------------- pass B: replay recurrence from bf16 b (Bb), prefetched; fp32 h -> d_out.
__global__ __launch_bounds__(64) void scan_passB(const short* __restrict__ bws,
                                                 const float* __restrict__ hIn,
                                                 float* __restrict__ hout) {
  int bc = blockIdx.x;
  int l = threadIdx.x;
  int row0 = bc * LC;
  const float* hp = hIn + (size_t)bc * HOUT + l * 8;
  float h[8];
  #pragma unroll
  for (int i = 0; i < 8; ++i) h[i] = hp[i];
  s16x8 vc = *reinterpret_cast<const s16x8*>(bws + (size_t)row0 * HOUT + l * 8);
  for (int t = 0; t < LC; ++t) {
    s16x8 vn;
    if (t + 1 < LC)
      vn = *reinterpret_cast<const s16x8*>(bws + (size_t)(row0 + t + 1) * HOUT + l * 8);
    float bb[8];
    #pragma unroll
    for (int i = 0; i < 8; ++i) bb[i] = bf2f(vc[i]);
    float ph = __shfl(h[7], (l + 63) & 63);
    #pragma unroll
    for (int i = 7; i >= 1; --i) h[i] = fmaxf(0.f, bb[i] + h[i - 1]);
    h[0] = fmaxf(0.f, bb[0] + ph);
    f32x4 o0, o1;
    #pragma unroll
    for (int i = 0; i < 4; ++i) { o0[i] = h[i]; o1[i] = h[4 + i]; }
    float* bt = hout + (size_t)(row0 + t) * HOUT + l * 8;
    *reinterpret_cast<f32x4*>(bt) = o0;
    *reinterpret_cast<f32x4*>(bt + 4) = o1;
    vc = vn;
  }
}

extern "C" void kernel_launch(void* const* d_in, const int* in_sizes, int n_in,
                              void* d_out, int out_size, void* d_ws, size_t ws_size,
                              hipStream_t stream) {
  (void)in_sizes; (void)n_in; (void)out_size; (void)ws_size;
  const float* x      = (const float*)d_in[0];
  const float* hidden = (const float*)d_in[1];
  const float* lin0W  = (const float*)d_in[2];
  const float* lin0b  = (const float*)d_in[3];
  const float* sig0W  = (const float*)d_in[4];
  const float* sig0b  = (const float*)d_in[5];
  const float* fchW   = (const float*)d_in[6];
  const float* fchb   = (const float*)d_in[7];
  const float* fc2W   = (const float*)d_in[8];
  const float* fc2b   = (const float*)d_in[9];
  float* outO  = (float*)d_out;
  float* lastO = outO + (size_t)NROWS * HOUT;

  char* wsb = (char*)d_ws;
  size_t off = 0;
  auto alloc = [&](size_t bytes) { char* p = wsb + off; off += (bytes + 255) & ~(size_t)255; return p; };
  float* Cc  = (float*)alloc((size_t)NBATCH * NC * HOUT * 4);
  float* Sc  = (float*)alloc((size_t)NBATCH * NC * HOUT * 4);
  float* hIn = (float*)alloc((size_t)NBATCH * NC * HOUT * 4);
  short* W1h = (short*)alloc(HY * KIN * 2);
  short* W2h = (short*)alloc(HY * KIN * 2);
  short* Fh  = (short*)alloc(HOUT * HY * 2);
  short* F2h = (short*)alloc(HOUT * KIN * 2);
  short* Gh  = (short*)alloc((size_t)NROWS * HY * 2);
  short* xh  = (short*)alloc((size_t)NROWS * KIN * 2);
  short* Bb  = (short*)alloc((size_t)NROWS * HOUT * 2);

  prep_w<<<704, 256, 0, stream>>>(lin0W, sig0W, fchW, fc2W, W1h, W2h, Fh, F2h);
  gx<<<NROWS / 64, 256, 0, stream>>>(x, W1h, W2h, lin0b, sig0b, Gh, xh);
  bg<<<2048, 512, 0, stream>>>(xh, Gh, F2h, Fh, fchb, fc2b, Bb);
  scan_passA<<<NBATCH * NC, 64, 0, stream>>>(Bb, Cc, Sc);
  scan_combine<<<NBATCH, 64, 0, stream>>>(hidden, Cc, Sc, hIn, lastO);
  scan_passB<<<NBATCH * NC, 64, 0, stream>>>(Bb, hIn, outO);
}

// Round 24
// 148.669 us; speedup vs baseline: 1.0710x; 1.0425x over previous
//
#include <hip/hip_runtime.h>

typedef __attribute__((ext_vector_type(4))) float  f32x4;
typedef __attribute__((ext_vector_type(4))) short  s16x4;
typedef __attribute__((ext_vector_type(8))) short  s16x8;
typedef __bf16 bf16x8 __attribute__((ext_vector_type(8)));

#define NBATCH 16
#define SEQ    4096
#define KIN    256
#define HY     64
#define HOUT   512
#define NROWS  (NBATCH*SEQ)   /* 65536 */
#define LC     64
#define NC     (SEQ/LC)       /* 64 */

#define GP(x) ((const __attribute__((address_space(1))) void*)(x))
#define LP(x) ((__attribute__((address_space(3))) void*)(x))

static __device__ __forceinline__ short f2bf(float f) {
  unsigned u = __float_as_uint(f);
  u = u + 0x7FFF + ((u >> 16) & 1);          // RNE
  return (short)(u >> 16);
}
static __device__ __forceinline__ float bf2f(short h) {
  return __uint_as_float(((unsigned)(unsigned short)h) << 16);
}
static __device__ __forceinline__ f32x4 mfma16(bf16x8 a, bf16x8 b, f32x4 c) {
  return __builtin_amdgcn_mfma_f32_16x16x32_bf16(a, b, c, 0, 0, 0);
}
static __device__ __forceinline__ bf16x8 ldfrag(const short* p) {
  return *reinterpret_cast<const bf16x8*>(p);
}
static __device__ __forceinline__ float fsigmoid(float z) {
  return 1.f / (1.f + __expf(-z));
}

// ---------------- weight prep (all plain bf16)
__global__ void prep_w(const float* __restrict__ lin0W, const float* __restrict__ sig0W,
                       const float* __restrict__ fchW,  const float* __restrict__ fc2W,
                       short* __restrict__ W1h, short* __restrict__ W2h,
                       short* __restrict__ Fh,  short* __restrict__ F2h) {
  int i = blockIdx.x * 256 + threadIdx.x;
  if (i < 16384) {
    W1h[i] = f2bf(lin0W[i]);
    W2h[i] = f2bf(sig0W[i]);
  } else if (i < 16384 + 32768) {
    Fh[i - 16384] = f2bf(fchW[i - 16384]);
  } else if (i < 16384 + 32768 + 131072) {
    F2h[i - 49152] = f2bf(fc2W[i - 49152]);
  }
}

// ---------------- gx: 64-row blocks. g = relu((x@lin0^T+b)*sigmoid(x@sig0^T+b)) -> Gh (bf16,
// LDS-bounced coalesced), and xh = bf16(x) emitted during staging (16B stores). (r13-verified)
__global__ __launch_bounds__(256) void gx(
    const float* __restrict__ x,
    const short* __restrict__ W1h, const short* __restrict__ W2h,
    const float* __restrict__ lin0b, const float* __restrict__ sig0b,
    short* __restrict__ Gh, short* __restrict__ xh) {
  __shared__ __align__(16) short smem[64 * 256 + 64 * 64];  // Ah 32KB + gL 8KB
  short* Ah = smem;
  short* gL = smem + 64 * 256;
  int tid = threadIdx.x;
  int row0 = blockIdx.x * 64;
  #pragma unroll
  for (int i = 0; i < 8; ++i) {
    int slot = i * 256 + tid;              // 2048 slots of 8 floats over 64x256
    int r = slot >> 5, k8 = slot & 31;
    const float* xp = x + (size_t)(row0 + r) * KIN + k8 * 8;
    f32x4 v0 = *reinterpret_cast<const f32x4*>(xp);
    f32x4 v1 = *reinterpret_cast<const f32x4*>(xp + 4);
    s16x8 hh;
    #pragma unroll
    for (int j = 0; j < 4; ++j) { hh[j] = f2bf(v0[j]); hh[4 + j] = f2bf(v1[j]); }
    *reinterpret_cast<s16x8*>(&Ah[(r * 256 + k8 * 8) ^ ((r & 7) << 3)]) = hh;
    *reinterpret_cast<s16x8*>(xh + (size_t)(row0 + r) * KIN + k8 * 8) = hh;
  }
  __syncthreads();
  int w = tid >> 6, l = tid & 63, lr = l & 15, lg = l >> 4;
  {
    int c = w * 16 + lr;
    f32x4 a1[4], a2[4];
    #pragma unroll
    for (int rt = 0; rt < 4; ++rt) { a1[rt] = (f32x4)0.f; a2[rt] = (f32x4)0.f; }
    #pragma unroll
    for (int ks = 0; ks < 8; ++ks) {
      int kk = ks * 32 + lg * 8;
      bf16x8 b1 = ldfrag(W1h + c * 256 + kk);
      bf16x8 b2 = ldfrag(W2h + c * 256 + kk);
      #pragma unroll
      for (int rt = 0; rt < 4; ++rt) {
        int r = rt * 16 + lr;
        bf16x8 a = ldfrag(&Ah[(r * 256 + kk) ^ ((r & 7) << 3)]);
        a1[rt] = mfma16(b1, a, a1[rt]);
        a2[rt] = mfma16(b2, a, a2[rt]);
      }
    }
    f32x4 blv = *reinterpret_cast<const f32x4*>(lin0b + w * 16 + lg * 4);
    f32x4 bsv = *reinterpret_cast<const f32x4*>(sig0b + w * 16 + lg * 4);
    #pragma unroll
    for (int rt = 0; rt < 4; ++rt) {
      int xrl = rt * 16 + lr;                // local x row
      s16x4 gg;
      #pragma unroll
      for (int j = 0; j < 4; ++j) {
        float g = (a1[rt][j] + blv[j]) * fsigmoid(a2[rt][j] + bsv[j]);
        gg[j] = f2bf(g > 0.f ? g : 0.f);
      }
      *reinterpret_cast<s16x4*>(&gL[(xrl * 64 + w * 16 + lg * 4) ^ ((xrl & 7) << 3)]) = gg;
    }
  }
  __syncthreads();
  #pragma unroll
  for (int i = 0; i < 2; ++i) {
    int slot = i * 256 + tid;
    int row = slot >> 3, c8 = slot & 7;
    s16x8 v = *reinterpret_cast<const s16x8*>(&gL[(row * 64 + c8 * 8) ^ ((row & 7) << 3)]);
    *reinterpret_cast<s16x8*>(Gh + (size_t)(row0 + row) * HY + c8 * 8) = v;
  }
}

// ---------------- bg: 128x128 staged GEMM, 512 threads / 8 waves (wave = 32x64 quadrant),
// double-buffered 2x32KB LDS, 2-phase schedule. Col-sweep mapping (r16-measured FETCH win):
// 4 col-blocks of each xh row-panel run consecutively on ONE XCD -> panel fetched once into L2.
__global__ __launch_bounds__(512, 4) void bg(
    const short* __restrict__ xh, const short* __restrict__ Gh,
    const short* __restrict__ F2h, const short* __restrict__ Fh,
    const float* __restrict__ fchb, const float* __restrict__ fc2b,
    short* __restrict__ Bb) {
  __shared__ __align__(16) short smem[2][16384];   // 2 x 32KB (As 8192 + Bs 8192 shorts each)
  short* bT = &smem[1][0];                          // 128x128 shorts = 32KB (bounce phase, buf1)
  int tid = threadIdx.x;
  int w = tid >> 6, l = tid & 63;
  int lr = l & 15, lg = l >> 4;
  int r0 = (w >> 1) * 32;                           // 4 row-quarters of 32
  int c0 = (w & 1) * 64;                            // 2 col-halves of 64
  int bid = blockIdx.x;
  int xcd = bid & 7, idx = bid >> 3;
  int rowTile = (xcd << 6) + (idx >> 2);            // bijective over [0,512)
  int colTile = idx & 3;                            // col-sweep within XCD
  int row0 = rowTile * 128;
  int col0 = colTile * 128;

  auto stage = [&](int t, int b) {
    short* As = &smem[b][0];
    short* Bs = &smem[b][8192];
    #pragma unroll
    for (int j = 0; j < 2; ++j) {
      int blk = w * 2 + j;                          // 16 slot-blocks of 64 slots
      int flat = blk * 64 + l;                      // 16B slot in [0,1024)
      int row = flat >> 3, sp = flat & 7;
      int seg = sp ^ (row & 7);                     // inverse of read-side XOR
      const short* asrc = (t < 4) ? xh + (size_t)(row0 + row) * KIN + t * 64 + seg * 8
                                  : Gh + (size_t)(row0 + row) * HY + seg * 8;
      const short* bsrc = (t < 4) ? F2h + (size_t)(col0 + row) * KIN + t * 64 + seg * 8
                                  : Fh + (size_t)(col0 + row) * HY + seg * 8;
      __builtin_amdgcn_global_load_lds(GP(asrc), LP(&As[blk * 512]), 16, 0, 0);
      __builtin_amdgcn_global_load_lds(GP(bsrc), LP(&Bs[blk * 512]), 16, 0, 0);
    }
  };
  auto compute = [&](int b, f32x4 (&acc)[2][4]) {
    short* As = &smem[b][0];
    short* Bs = &smem[b][8192];
    #pragma unroll
    for (int ksl = 0; ksl < 2; ++ksl) {
      bf16x8 Af[2], Bf[4];
      #pragma unroll
      for (int i = 0; i < 2; ++i) {
        int row = r0 + i * 16 + lr;
        Af[i] = ldfrag(&As[row * 64 + ((ksl * 32 + lg * 8) ^ ((row & 7) << 3))]);
      }
      #pragma unroll
      for (int i = 0; i < 4; ++i) {
        int col = c0 + i * 16 + lr;
        Bf[i] = ldfrag(&Bs[col * 64 + ((ksl * 32 + lg * 8) ^ ((col & 7) << 3))]);
      }
      #pragma unroll
      for (int rt = 0; rt < 2; ++rt)
        #pragma unroll
        for (int ct = 0; ct < 4; ++ct)
          acc[rt][ct] = mfma16(Af[rt], Bf[ct], acc[rt][ct]);
    }
  };

  f32x4 acc2[2][4], accF[2][4];
  #pragma unroll
  for (int rt = 0; rt < 2; ++rt)
    #pragma unroll
    for (int ct = 0; ct < 4; ++ct) { acc2[rt][ct] = (f32x4)0.f; accF[rt][ct] = (f32x4)0.f; }

  stage(0, 0);
  __syncthreads();                        // buf0 ready
  #pragma unroll
  for (int t = 0; t < 4; ++t) {
    stage(t + 1, (t + 1) & 1);            // issue next-tile loads into other buffer
    compute(t & 1, acc2);
    __syncthreads();                      // drains prefetch vmcnt; next buf ready
  }
  compute(0, accF);                       // buf0; no trailing barrier (bT = buf1, free)

  // epilogue: gate -> bf16 -> swizzled bT (buf1)
  #pragma unroll
  for (int ct = 0; ct < 4; ++ct) {
    int lc = c0 + ct * 16 + lr;
    int col = col0 + lc;
    float bc = fchb[col], b2c = fc2b[col];
    #pragma unroll
    for (int rt = 0; rt < 2; ++rt) {
      int tl0 = r0 + rt * 16 + lg * 4;
      #pragma unroll
      for (int j = 0; j < 4; ++j) {
        int tl = tl0 + j;
        float alpha = fsigmoid(acc2[rt][ct][j] + b2c);
        bT[(tl * 128 + lc) ^ ((tl & 7) << 3)] = f2bf((accF[rt][ct][j] + bc) * alpha);
      }
    }
  }
  __syncthreads();
  // coalesced store: 2048 slots of 16B over 128x128 shorts
  #pragma unroll
  for (int i = 0; i < 4; ++i) {
    int slot = i * 512 + tid;
    int row = slot >> 4, c8 = slot & 15;
    s16x8 vv = *reinterpret_cast<const s16x8*>(&bT[(row * 128 + c8 * 8) ^ ((row & 7) << 3)]);
    *reinterpret_cast<s16x8*>(Bb + (size_t)(row0 + row) * HOUT + col0 + c8 * 8) = vv;
  }
}

// ---------------- passA: per-chunk (LC=64 rows) max-plus operator (C,S). 1 wave/chunk, prefetched.
__global__ __launch_bounds__(64) void scan_passA(const short* __restrict__ Bb,
                                                 float* __restrict__ Cc, float* __restrict__ Sc) {
  int bc = blockIdx.x;
  int l = threadIdx.x;
  int row0 = bc * LC;
  const short* bp = Bb + (size_t)row0 * HOUT + l * 8;
  s16x8 v0 = *reinterpret_cast<const s16x8*>(bp);
  float C[8], S[8];
  #pragma unroll
  for (int i = 0; i < 8; ++i) { S[i] = bf2f(v0[i]); C[i] = 0.f; }
  s16x8 vc = *reinterpret_cast<const s16x8*>(bp + (size_t)HOUT);   // row 1
  for (int t = 1; t < LC; ++t) {
    s16x8 vn;
    if (t + 1 < LC) vn = *reinterpret_cast<const s16x8*>(bp + (size_t)(t + 1) * HOUT);
    float bb[8];
    #pragma unroll
    for (int i = 0; i < 8; ++i) bb[i] = bf2f(vc[i]);
    float pC = __shfl(C[7], (l + 63) & 63);
    float pS = __shfl(S[7], (l + 63) & 63);
    #pragma unroll
    for (int i = 7; i >= 1; --i) { C[i] = fmaxf(0.f, bb[i] + C[i - 1]); S[i] = bb[i] + S[i - 1]; }
    C[0] = fmaxf(0.f, bb[0] + pC);
    S[0] = bb[0] + pS;
    vc = vn;
  }
  float* cp = Cc + (size_t)bc * HOUT + l * 8;
  float* sp = Sc + (size_t)bc * HOUT + l * 8;
  #pragma unroll
  for (int i = 0; i < 8; ++i) { cp[i] = C[i]; sp[i] = S[i]; }
}

// ---------------- combine: sequential over NC=64 chunks per batch, prefetch depth 4.
__global__ __launch_bounds__(64) void scan_combine(const float* __restrict__ hidden,
                                                   const float* __restrict__ Cc, const float* __restrict__ Sc,
                                                   float* __restrict__ hIn, float* __restrict__ lastOut) {
  int batch = blockIdx.x;
  int l = threadIdx.x;
  float h[8];
  const float* hp = hidden + batch * HOUT + l * 8;
  #pragma unroll
  for (int i = 0; i < 8; ++i) h[i] = hp[i];
  size_t base0 = ((size_t)batch * NC) * HOUT + l * 8;
  f32x4 pc0[4], pc1[4], ps0[4], ps1[4];
  #pragma unroll
  for (int s = 0; s < 4; ++s) {
    size_t b = base0 + (size_t)s * HOUT;
    pc0[s] = *reinterpret_cast<const f32x4*>(Cc + b);
    pc1[s] = *reinterpret_cast<const f32x4*>(Cc + b + 4);
    ps0[s] = *reinterpret_cast<const f32x4*>(Sc + b);
    ps1[s] = *reinterpret_cast<const f32x4*>(Sc + b + 4);
  }
  for (int cg = 0; cg < NC; cg += 4) {
    #pragma unroll
    for (int s = 0; s < 4; ++s) {
      int c = cg + s;
      size_t base = base0 + (size_t)c * HOUT;
      f32x4 h0, h1;
      #pragma unroll
      for (int i = 0; i < 4; ++i) { h0[i] = h[i]; h1[i] = h[4 + i]; }
      *reinterpret_cast<f32x4*>(hIn + base) = h0;
      *reinterpret_cast<f32x4*>(hIn + base + 4) = h1;
      float hs[8];
      #pragma unroll
      for (int i = 0; i < 8; ++i) hs[i] = __shfl(h[i], (l + 64 - (LC / 8)) & 63);   // d - LC
      #pragma unroll
      for (int i = 0; i < 4; ++i) {
        h[i]     = fmaxf(pc0[s][i], ps0[s][i] + hs[i]);
        h[4 + i] = fmaxf(pc1[s][i], ps1[s][i] + hs[4 + i]);
      }
      if (c + 4 < NC) {
        size_t nb = base + (size_t)4 * HOUT;
        pc0[s] = *reinterpret_cast<const f32x4*>(Cc + nb);
        pc1[s] = *reinterpret_cast<const f32x4*>(Cc + nb + 4);
        ps0[s] = *reinterpret_cast<const f32x4*>(Sc + nb);
        ps1[s] = *reinterpret_cast<const f32x4*>(Sc + nb + 4);
      }
    }
  }
  float* lp = lastOut + batch * HOUT + l * 8;
  #pragma unroll
  for (int i = 0; i < 8; ++i) lp[i] = h[i];
}

// ---------------- pass B: replay recurrence from bf16 b (Bb), prefetched; fp32 h -> d_out.
__global__ __launch_bounds__(64) void scan_passB(const short* __restrict__ bws,
                                                 const float* __restrict__ hIn,
                                                 float* __restrict__ hout) {
  int bc = blockIdx.x;
  int l = threadIdx.x;
  int row0 = bc * LC;
  const float* hp = hIn + (size_t)bc * HOUT + l * 8;
  float h[8];
  #pragma unroll
  for (int i = 0; i < 8; ++i) h[i] = hp[i];
  s16x8 vc = *reinterpret_cast<const s16x8*>(bws + (size_t)row0 * HOUT + l * 8);
  for (int t = 0; t < LC; ++t) {
    s16x8 vn;
    if (t + 1 < LC)
      vn = *reinterpret_cast<const s16x8*>(bws + (size_t)(row0 + t + 1) * HOUT + l * 8);
    float bb[8];
    #pragma unroll
    for (int i = 0; i < 8; ++i) bb[i] = bf2f(vc[i]);
    float ph = __shfl(h[7], (l + 63) & 63);
    #pragma unroll
    for (int i = 7; i >= 1; --i) h[i] = fmaxf(0.f, bb[i] + h[i - 1]);
    h[0] = fmaxf(0.f, bb[0] + ph);
    f32x4 o0, o1;
    #pragma unroll
    for (int i = 0; i < 4; ++i) { o0[i] = h[i]; o1[i] = h[4 + i]; }
    float* bt = hout + (size_t)(row0 + t) * HOUT + l * 8;
    *reinterpret_cast<f32x4*>(bt) = o0;
    *reinterpret_cast<f32x4*>(bt + 4) = o1;
    vc = vn;
  }
}

extern "C" void kernel_launch(void* const* d_in, const int* in_sizes, int n_in,
                              void* d_out, int out_size, void* d_ws, size_t ws_size,
                              hipStream_t stream) {
  (void)in_sizes; (void)n_in; (void)out_size; (void)ws_size;
  const float* x      = (const float*)d_in[0];
  const float* hidden = (const float*)d_in[1];
  const float* lin0W  = (const float*)d_in[2];
  const float* lin0b  = (const float*)d_in[3];
  const float* sig0W  = (const float*)d_in[4];
  const float* sig0b  = (const float*)d_in[5];
  const float* fchW   = (const float*)d_in[6];
  const float* fchb   = (const float*)d_in[7];
  const float* fc2W   = (const float*)d_in[8];
  const float* fc2b   = (const float*)d_in[9];
  float* outO  = (float*)d_out;
  float* lastO = outO + (size_t)NROWS * HOUT;

  char* wsb = (char*)d_ws;
  size_t off = 0;
  auto alloc = [&](size_t bytes) { char* p = wsb + off; off += (bytes + 255) & ~(size_t)255; return p; };
  float* Cc  = (float*)alloc((size_t)NBATCH * NC * HOUT * 4);
  float* Sc  = (float*)alloc((size_t)NBATCH * NC * HOUT * 4);
  float* hIn = (float*)alloc((size_t)NBATCH * NC * HOUT * 4);
  short* W1h = (short*)alloc(HY * KIN * 2);
  short* W2h = (short*)alloc(HY * KIN * 2);
  short* Fh  = (short*)alloc(HOUT * HY * 2);
  short* F2h = (short*)alloc(HOUT * KIN * 2);
  short* Gh  = (short*)alloc((size_t)NROWS * HY * 2);
  short* xh  = (short*)alloc((size_t)NROWS * KIN * 2);
  short* Bb  = (short*)alloc((size_t)NROWS * HOUT * 2);

  prep_w<<<704, 256, 0, stream>>>(lin0W, sig0W, fchW, fc2W, W1h, W2h, Fh, F2h);
  gx<<<NROWS / 64, 256, 0, stream>>>(x, W1h, W2h, lin0b, sig0b, Gh, xh);
  bg<<<2048, 512, 0, stream>>>(xh, Gh, F2h, Fh, fchb, fc2b, Bb);
  scan_passA<<<NBATCH * NC, 64, 0, stream>>>(Bb, Cc, Sc);
  scan_combine<<<NBATCH, 64, 0, stream>>>(hidden, Cc, Sc, hIn, lastO);
  scan_passB<<<NBATCH * NC, 64, 0, stream>>>(Bb, hIn, outO);
}